// Round 8
// baseline (360.386 us; speedup 1.0000x reference)
//
#include <hip/hip_runtime.h>

typedef __bf16 bf16;
typedef __bf16 bf16x4 __attribute__((ext_vector_type(4)));
typedef __bf16 bf16x8 __attribute__((ext_vector_type(8)));
typedef float f32x4 __attribute__((ext_vector_type(4)));

#define B_SZ 32768
#define T_CAT 26
#define V_SZ 100000
#define E_SZ 128

__device__ __forceinline__ void gload_lds16(const void* g, void* l) {
    __builtin_amdgcn_global_load_lds(
        (const __attribute__((address_space(1))) void*)g,
        (__attribute__((address_space(3))) void*)l, 16, 0, 0);
}

// ---------------------------------------------------------------------------
// Merged weight convert with LDS transpose: W (K x N fp32) -> Wt (N x Kp bf16).
// ---------------------------------------------------------------------------
struct CJob { const float* W; bf16* Wt; int K, N, Kp, blk0, tk; };
struct CJobs { CJob j[7]; };

__global__ __launch_bounds__(256) void convw_all(CJobs js) {
    __shared__ bf16 tile[64][66];
    const int b = blockIdx.x;
    int ji = 0;
#pragma unroll
    for (int k = 1; k < 7; ++k)
        if (b >= js.j[k].blk0) ji = k;
    const CJob J = js.j[ji];
    const int local = b - J.blk0;
    const int tn = local / J.tk;
    const int tkk = local - tn * J.tk;

    const int t = threadIdx.x;
    const int lx = t & 63;
    const int gy = t >> 6;

#pragma unroll
    for (int kk = 0; kk < 16; ++kk) {
        const int k = tkk * 64 + kk * 4 + gy;
        const int n = tn * 64 + lx;
        const float v = (k < J.K) ? J.W[(long)k * J.N + n] : 0.0f;
        tile[lx][kk * 4 + gy] = (bf16)v;
    }
    __syncthreads();
#pragma unroll
    for (int nn = 0; nn < 16; ++nn) {
        const int nloc = nn * 4 + gy;
        const int n = tn * 64 + nloc;
        const int k = tkk * 64 + lx;
        J.Wt[(long)n * J.Kp + k] = tile[nloc][lx];
    }
}

// numerical (B x 13 fp32) -> xpad (B x 64 bf16)
__global__ __launch_bounds__(256) void make_xpad(const float* __restrict__ num,
                                                 bf16* __restrict__ xp) {
    const int idx = blockIdx.x * 256 + threadIdx.x;
    const int b = idx >> 6, c = idx & 63;
    xp[idx] = (bf16)((c < 13) ? num[(long)b * 13 + c] : 0.0f);
}

// ---------------------------------------------------------------------------
// 128x128 tile GEMM (m97 structure, 16x16x32 MFMA) — small-N layers (l0, l2).
// ---------------------------------------------------------------------------
template <int RELU>
__global__ __launch_bounds__(256) void gemm_bt(const bf16* __restrict__ A,
                                               const bf16* __restrict__ Bt,
                                               const float* __restrict__ bias,
                                               bf16* __restrict__ C,
                                               int M, int N, int K) {
    __shared__ __align__(16) bf16 As[128 * 64];
    __shared__ __align__(16) bf16 Bs[128 * 64];
    const int t = threadIdx.x;
    const int lane = t & 63;
    const int w = t >> 6;
    const int wm = w >> 1, wn = w & 1;
    const long row0 = (long)blockIdx.y * 128;
    const long col0 = (long)blockIdx.x * 128;

    const int srow = t >> 3;
    const int scol = (t & 7) * 8;
    const bf16* Ag = A + (row0 + srow) * (long)K + scol;
    const bf16* Bg = Bt + (col0 + srow) * (long)K + scol;
    bf16* AsB = &As[w * 512];
    bf16* BsB = &Bs[w * 512];

    f32x4 acc[4][4] = {};

    for (int k0 = 0; k0 < K; k0 += 64) {
#pragma unroll
        for (int q = 0; q < 4; ++q) {
            gload_lds16(Ag + (long)q * 32 * K + k0, AsB + q * 2048);
            gload_lds16(Bg + (long)q * 32 * K + k0, BsB + q * 2048);
        }
        __syncthreads();
#pragma unroll
        for (int s = 0; s < 2; ++s) {
            bf16x8 af[4], bv[4];
#pragma unroll
            for (int i = 0; i < 4; ++i)
                af[i] = *(const bf16x8*)&As[(wm * 64 + i * 16 + (lane & 15)) * 64 +
                                            s * 32 + (lane >> 4) * 8];
#pragma unroll
            for (int j = 0; j < 4; ++j)
                bv[j] = *(const bf16x8*)&Bs[(wn * 64 + j * 16 + (lane & 15)) * 64 +
                                            s * 32 + (lane >> 4) * 8];
#pragma unroll
            for (int i = 0; i < 4; ++i)
#pragma unroll
                for (int j = 0; j < 4; ++j)
                    acc[i][j] = __builtin_amdgcn_mfma_f32_16x16x32_bf16(
                        af[i], bv[j], acc[i][j], 0, 0, 0);
        }
        __syncthreads();
    }

    const int r4 = (lane >> 4) * 4;
    const int cn = lane & 15;
#pragma unroll
    for (int j = 0; j < 4; ++j) {
        const long col = col0 + wn * 64 + j * 16 + cn;
        const float bj = bias[col];
#pragma unroll
        for (int i = 0; i < 4; ++i) {
#pragma unroll
            for (int r = 0; r < 4; ++r) {
                const long row = row0 + wm * 64 + i * 16 + r4 + r;
                float v = acc[i][j][r] + bj;
                if (RELU) v = v > 0.0f ? v : 0.0f;
                C[row * (long)N + col] = (bf16)v;
            }
        }
    }
}

// ---------------------------------------------------------------------------
// 256x128 tile GEMM, BK=64, 2-barrier loop, 16x16x32 MFMA, 8 waves (4m x 2n),
// wave tile 64x64 (R6 winner) — mid-size layers (l1, t3).
// ---------------------------------------------------------------------------
template <int RELU>
__global__ __launch_bounds__(512, 4) void gemm_bt2(const bf16* __restrict__ A,
                                                   const bf16* __restrict__ Bt,
                                                   const float* __restrict__ bias,
                                                   bf16* __restrict__ C,
                                                   int M, int N, int K, int nbx) {
    __shared__ __align__(16) bf16 As[256 * 64];  // 32 KB
    __shared__ __align__(16) bf16 Bs[128 * 64];  // 16 KB
    const int t = threadIdx.x;
    const int lane = t & 63;
    const int w = t >> 6;            // 0..7
    const int wm = w >> 1, wn = w & 1;

    const int nwg = gridDim.x;
    const int qch = nwg >> 3;
    const int swz = ((int)blockIdx.x & 7) * qch + ((int)blockIdx.x >> 3);
    const int bx = swz % nbx, by = swz / nbx;
    const long row0 = (long)by * 256;
    const long col0 = (long)bx * 128;

    const int srow = t >> 3;   // 0..63
    const int dslot = t & 7;
    const int gsl = dslot ^ (srow & 7);
    const bf16* Ag = A + (row0 + srow) * (long)K + gsl * 8;
    const bf16* Bg = Bt + (col0 + srow) * (long)K + gsl * 8;
    bf16* AsB = &As[w * 512];
    bf16* BsB = &Bs[w * 512];

    const int cm = lane & 15;
    const int kc = lane >> 4;

    f32x4 acc[4][4] = {};

    for (int k0 = 0; k0 < K; k0 += 64) {
#pragma unroll
        for (int q = 0; q < 4; ++q)
            gload_lds16(Ag + (long)q * 64 * K + k0, AsB + q * 4096);
#pragma unroll
        for (int q = 0; q < 2; ++q)
            gload_lds16(Bg + (long)q * 64 * K + k0, BsB + q * 4096);
        __syncthreads();
#pragma unroll
        for (int s = 0; s < 2; ++s) {
            bf16x8 af[4], bv[4];
#pragma unroll
            for (int i = 0; i < 4; ++i) {
                const int r = wm * 64 + i * 16 + cm;
                af[i] = *(const bf16x8*)&As[r * 64 + (((s * 4 + kc) ^ (r & 7)) * 8)];
            }
#pragma unroll
            for (int j = 0; j < 4; ++j) {
                const int r = wn * 64 + j * 16 + cm;
                bv[j] = *(const bf16x8*)&Bs[r * 64 + (((s * 4 + kc) ^ (r & 7)) * 8)];
            }
#pragma unroll
            for (int i = 0; i < 4; ++i)
#pragma unroll
                for (int j = 0; j < 4; ++j)
                    acc[i][j] = __builtin_amdgcn_mfma_f32_16x16x32_bf16(
                        af[i], bv[j], acc[i][j], 0, 0, 0);
        }
        __syncthreads();
    }

    const int r4 = kc * 4;
#pragma unroll
    for (int j = 0; j < 4; ++j) {
        const long col = col0 + wn * 64 + j * 16 + cm;
        const float bj = bias[col];
#pragma unroll
        for (int i = 0; i < 4; ++i) {
#pragma unroll
            for (int r = 0; r < 4; ++r) {
                const long row = row0 + wm * 64 + i * 16 + r4 + r;
                float v = acc[i][j][r] + bj;
                if (RELU) v = v > 0.0f ? v : 0.0f;
                C[row * (long)N + col] = (bf16)v;
            }
        }
    }
}

// ---------------------------------------------------------------------------
// 256x128 tile GEMM, BK=64, 2-barrier loop, 4 waves (2m x 2n), wave tile
// 128x64: LDS reads per block-K-tile drop 128->96 KB (register reuse), total
// LDS traffic -18% vs gemm_bt2 — attacks the LDS-BW bound. acc = 128 VGPR;
// __launch_bounds__(256,2) -> <=256 VGPR -> 2 blocks/CU (LDS 96/160 KB).
// 32 independent MFMAs per s-step give per-wave ILP; 2-block overlap hides
// barriers (m114). Same both-sides XOR swizzle as gemm_bt2.
// Requires M%256==0, N%128==0, K%64==0, grid%8==0.
// ---------------------------------------------------------------------------
template <int RELU>
__global__ __launch_bounds__(256, 2) void gemm_bt3(const bf16* __restrict__ A,
                                                   const bf16* __restrict__ Bt,
                                                   const float* __restrict__ bias,
                                                   bf16* __restrict__ C,
                                                   int M, int N, int K, int nbx) {
    __shared__ __align__(16) bf16 As[256 * 64];  // 32 KB
    __shared__ __align__(16) bf16 Bs[128 * 64];  // 16 KB
    const int t = threadIdx.x;
    const int lane = t & 63;
    const int w = t >> 6;            // 0..3
    const int wm = w >> 1, wn = w & 1;

    const int nwg = gridDim.x;
    const int qch = nwg >> 3;
    const int swz = ((int)blockIdx.x & 7) * qch + ((int)blockIdx.x >> 3);
    const int bx = swz % nbx, by = swz / nbx;
    const long row0 = (long)by * 256;
    const long col0 = (long)bx * 128;

    // staging: 256 threads; instr q covers 32 rows (q*32 + (t>>3)), slot t&7.
    const int srow = t >> 3;   // 0..31
    const int dslot = t & 7;
    const int gsl = dslot ^ (srow & 7);  // (q*32+srow)&7 == srow&7
    const bf16* Ag = A + (row0 + srow) * (long)K + gsl * 8;
    const bf16* Bg = Bt + (col0 + srow) * (long)K + gsl * 8;
    bf16* AsB = &As[w * 512];  // wave-uniform base; HW adds lane*16B
    bf16* BsB = &Bs[w * 512];

    const int cm = lane & 15;
    const int kc = lane >> 4;

    f32x4 acc[8][4] = {};

    for (int k0 = 0; k0 < K; k0 += 64) {
#pragma unroll
        for (int q = 0; q < 8; ++q)
            gload_lds16(Ag + (long)q * 32 * K + k0, AsB + q * 2048);
#pragma unroll
        for (int q = 0; q < 4; ++q)
            gload_lds16(Bg + (long)q * 32 * K + k0, BsB + q * 2048);
        __syncthreads();
#pragma unroll
        for (int s = 0; s < 2; ++s) {
            bf16x8 af[8], bv[4];
#pragma unroll
            for (int i = 0; i < 8; ++i) {
                const int r = wm * 128 + i * 16 + cm;
                af[i] = *(const bf16x8*)&As[r * 64 + (((s * 4 + kc) ^ (r & 7)) * 8)];
            }
#pragma unroll
            for (int j = 0; j < 4; ++j) {
                const int r = wn * 64 + j * 16 + cm;
                bv[j] = *(const bf16x8*)&Bs[r * 64 + (((s * 4 + kc) ^ (r & 7)) * 8)];
            }
#pragma unroll
            for (int i = 0; i < 8; ++i)
#pragma unroll
                for (int j = 0; j < 4; ++j)
                    acc[i][j] = __builtin_amdgcn_mfma_f32_16x16x32_bf16(
                        af[i], bv[j], acc[i][j], 0, 0, 0);
        }
        __syncthreads();
    }

    const int r4 = kc * 4;
#pragma unroll
    for (int j = 0; j < 4; ++j) {
        const long col = col0 + wn * 64 + j * 16 + cm;
        const float bj = bias[col];
#pragma unroll
        for (int i = 0; i < 8; ++i) {
#pragma unroll
            for (int r = 0; r < 4; ++r) {
                const long row = row0 + wm * 128 + i * 16 + r4 + r;
                float v = acc[i][j][r] + bj;
                if (RELU) v = v > 0.0f ? v : 0.0f;
                C[row * (long)N + col] = (bf16)v;
            }
        }
    }
}

// ---------------------------------------------------------------------------
// Fused embedding gather + pairwise interaction + top_in assembly.
// ---------------------------------------------------------------------------
__global__ __launch_bounds__(256) void interact_k(const float* __restrict__ emb,
                                                  const int* __restrict__ cat,
                                                  const bf16* __restrict__ bottom,
                                                  bf16* __restrict__ top_in) {
    __shared__ float gram[4][32 * 32];
    __shared__ __align__(16) bf16 rowbuf[4][512];
    const int t = threadIdx.x;
    const int lane = t & 63;
    const int w = t >> 6;
    const long s = (long)blockIdx.x * 4 + w;

    const int rl = lane & 15;
    const int kg = lane >> 4;

    bf16x8 f[2][4];
#pragma unroll
    for (int i = 0; i < 2; ++i) {
        const int r = i * 16 + rl;
        const float* rowp = nullptr;
        if (r >= 1 && r <= 26) {
            const int idx = cat[s * T_CAT + (r - 1)];
            rowp = emb + ((long)(r - 1) * V_SZ + idx) * E_SZ;
        }
#pragma unroll
        for (int ks = 0; ks < 4; ++ks) {
            const int c = ks * 32 + kg * 8;
            bf16x8 v = {};
            if (r == 0) {
                v = *(const bf16x8*)(bottom + s * 128 + c);
            } else if (r <= 26) {
                const float4 v0 = *(const float4*)(rowp + c);
                const float4 v1 = *(const float4*)(rowp + c + 4);
                v[0]=(bf16)v0.x; v[1]=(bf16)v0.y; v[2]=(bf16)v0.z; v[3]=(bf16)v0.w;
                v[4]=(bf16)v1.x; v[5]=(bf16)v1.y; v[6]=(bf16)v1.z; v[7]=(bf16)v1.w;
            }
            f[i][ks] = v;
        }
    }

    f32x4 a00 = {}, a01 = {}, a11 = {};
#pragma unroll
    for (int ks = 0; ks < 4; ++ks) {
        a00 = __builtin_amdgcn_mfma_f32_16x16x32_bf16(f[0][ks], f[0][ks], a00, 0, 0, 0);
        a01 = __builtin_amdgcn_mfma_f32_16x16x32_bf16(f[0][ks], f[1][ks], a01, 0, 0, 0);
        a11 = __builtin_amdgcn_mfma_f32_16x16x32_bf16(f[1][ks], f[1][ks], a11, 0, 0, 0);
    }

    const int r4 = kg * 4;
#pragma unroll
    for (int r = 0; r < 4; ++r) {
        gram[w][(r4 + r) * 32 + rl]           = a00[r];
        gram[w][(r4 + r) * 32 + 16 + rl]      = a01[r];
        gram[w][(16 + r4 + r) * 32 + 16 + rl] = a11[r];
    }
    asm volatile("s_waitcnt lgkmcnt(0)" ::: "memory");
    __builtin_amdgcn_sched_barrier(0);

    if (lane < 16)
        ((bf16x8*)&rowbuf[w][0])[lane] = ((const bf16x8*)(bottom + s * 128))[lane];
    for (int p = lane; p < 351; p += 64) {
        int i = 0, b = 0;
        while (b + (26 - i) <= p) { b += 26 - i; ++i; }
        const int j = p - b + i + 1;
        rowbuf[w][128 + p] = (bf16)gram[w][i * 32 + j];
    }
    if (lane >= 31) rowbuf[w][448 + lane] = (bf16)0.0f;
    asm volatile("s_waitcnt lgkmcnt(0)" ::: "memory");
    __builtin_amdgcn_sched_barrier(0);

    *(bf16x8*)(top_in + s * 512 + lane * 8) = *(const bf16x8*)&rowbuf[w][lane * 8];
}

// ---------------------------------------------------------------------------
// Final layer GEMV.
// ---------------------------------------------------------------------------
__global__ __launch_bounds__(256) void gemv_final(const bf16* __restrict__ A,
                                                  const float* __restrict__ w4,
                                                  const float* __restrict__ b4,
                                                  float* __restrict__ out) {
    const int t = threadIdx.x;
    const int lane = t & 63;
    const int w = t >> 6;
    const long m = (long)blockIdx.x * 4 + w;
    const bf16x4 v = *(const bf16x4*)(A + m * 256 + lane * 4);
    const float4 wv = *(const float4*)(w4 + lane * 4);
    float sum = (float)v[0] * wv.x + (float)v[1] * wv.y + (float)v[2] * wv.z +
                (float)v[3] * wv.w;
#pragma unroll
    for (int off = 32; off > 0; off >>= 1) sum += __shfl_down(sum, off);
    if (lane == 0) out[m] = sum + b4[0];
}

// ---------------------------------------------------------------------------
extern "C" void kernel_launch(void* const* d_in, const int* in_sizes, int n_in,
                              void* d_out, int out_size, void* d_ws, size_t ws_size,
                              hipStream_t stream) {
    const float* numerical = (const float*)d_in[0];
    const int*   cat       = (const int*)d_in[1];
    const float* emb       = (const float*)d_in[2];
    const float* bw0 = (const float*)d_in[3];
    const float* bb0 = (const float*)d_in[4];
    const float* bw1 = (const float*)d_in[5];
    const float* bb1 = (const float*)d_in[6];
    const float* bw2 = (const float*)d_in[7];
    const float* bb2 = (const float*)d_in[8];
    const float* tw0 = (const float*)d_in[9];
    const float* tb0 = (const float*)d_in[10];
    const float* tw1 = (const float*)d_in[11];
    const float* tb1 = (const float*)d_in[12];
    const float* tw2 = (const float*)d_in[13];
    const float* tb2 = (const float*)d_in[14];
    const float* tw3 = (const float*)d_in[15];
    const float* tb3 = (const float*)d_in[16];
    const float* tw4 = (const float*)d_in[17];
    const float* tb4 = (const float*)d_in[18];
    float* out = (float*)d_out;

    char* ws = (char*)d_ws;
    size_t off = 0;
    auto alloc = [&](size_t bytes) {
        char* p = ws + off;
        off += (bytes + 255) & ~(size_t)255;
        return p;
    };
    bf16* wt0b = (bf16*)alloc((size_t)512 * 64 * 2);
    bf16* wt1b = (bf16*)alloc((size_t)256 * 512 * 2);
    bf16* wt2b = (bf16*)alloc((size_t)128 * 256 * 2);
    bf16* wt0t = (bf16*)alloc((size_t)1024 * 512 * 2);
    bf16* wt1t = (bf16*)alloc((size_t)1024 * 1024 * 2);
    bf16* wt2t = (bf16*)alloc((size_t)512 * 1024 * 2);
    bf16* wt3t = (bf16*)alloc((size_t)256 * 512 * 2);
    bf16* xpad = (bf16*)alloc((size_t)B_SZ * 64 * 2);
    bf16* h0   = (bf16*)alloc((size_t)B_SZ * 512 * 2);
    bf16* h1   = (bf16*)alloc((size_t)B_SZ * 256 * 2);
    bf16* bot  = (bf16*)alloc((size_t)B_SZ * 128 * 2);
    bf16* t0   = (bf16*)alloc((size_t)B_SZ * 1024 * 2);
    bf16* t1   = (bf16*)alloc((size_t)B_SZ * 1024 * 2);
    bf16* top_in = h0;
    bf16* t2 = t0;
    bf16* t3 = t1;

    CJobs js;
    js.j[0] = {bw0, wt0b, 16, 512, 64, 0, 1};
    js.j[1] = {bw1, wt1b, 512, 256, 512, 8, 8};
    js.j[2] = {bw2, wt2b, 256, 128, 256, 40, 4};
    js.j[3] = {tw0, wt0t, 480, 1024, 512, 48, 8};
    js.j[4] = {tw1, wt1t, 1024, 1024, 1024, 176, 16};
    js.j[5] = {tw2, wt2t, 1024, 512, 1024, 432, 16};
    js.j[6] = {tw3, wt3t, 512, 256, 512, 560, 8};
    convw_all<<<592, 256, 0, stream>>>(js);

    make_xpad<<<(B_SZ * 64) / 256, 256, 0, stream>>>(numerical, xpad);

    // bottom MLP (R6 placement)
    gemm_bt<1><<<dim3(4, 256), 256, 0, stream>>>(xpad, wt0b, bb0, h0, B_SZ, 512, 64);
    gemm_bt2<1><<<dim3(256), 512, 0, stream>>>(h0, wt1b, bb1, h1, B_SZ, 256, 512, 2);
    gemm_bt<1><<<dim3(1, 256), 256, 0, stream>>>(h1, wt2b, bb2, bot, B_SZ, 128, 256);

    interact_k<<<B_SZ / 4, 256, 0, stream>>>(emb, cat, bot, top_in);

    // top MLP: big 3 layers on the 4-wave 128x64-wave-tile kernel
    gemm_bt3<1><<<dim3(1024), 256, 0, stream>>>(top_in, wt0t, tb0, t0, B_SZ, 1024, 512, 8);
    gemm_bt3<1><<<dim3(1024), 256, 0, stream>>>(t0, wt1t, tb1, t1, B_SZ, 1024, 1024, 8);
    gemm_bt3<1><<<dim3(512), 256, 0, stream>>>(t1, wt2t, tb2, t2, B_SZ, 512, 1024, 4);
    gemm_bt2<1><<<dim3(256), 512, 0, stream>>>(t2, wt3t, tb3, t3, B_SZ, 256, 512, 2);

    gemv_final<<<B_SZ / 4, 256, 0, stream>>>(t3, tw4, tb4, out);
}

// Round 9
// 336.804 us; speedup vs baseline: 1.0700x; 1.0700x over previous
//
#include <hip/hip_runtime.h>

typedef __bf16 bf16;
typedef __bf16 bf16x4 __attribute__((ext_vector_type(4)));
typedef __bf16 bf16x8 __attribute__((ext_vector_type(8)));
typedef float f32x4 __attribute__((ext_vector_type(4)));

#define B_SZ 32768
#define T_CAT 26
#define V_SZ 100000
#define E_SZ 128

__device__ __forceinline__ void gload_lds16(const void* g, void* l) {
    __builtin_amdgcn_global_load_lds(
        (const __attribute__((address_space(1))) void*)g,
        (__attribute__((address_space(3))) void*)l, 16, 0, 0);
}

// ---------------------------------------------------------------------------
// Merged weight convert with LDS transpose: W (K x N fp32) -> Wt (N x Kp bf16).
// ---------------------------------------------------------------------------
struct CJob { const float* W; bf16* Wt; int K, N, Kp, blk0, tk; };
struct CJobs { CJob j[7]; };

__global__ __launch_bounds__(256) void convw_all(CJobs js) {
    __shared__ bf16 tile[64][66];
    const int b = blockIdx.x;
    int ji = 0;
#pragma unroll
    for (int k = 1; k < 7; ++k)
        if (b >= js.j[k].blk0) ji = k;
    const CJob J = js.j[ji];
    const int local = b - J.blk0;
    const int tn = local / J.tk;
    const int tkk = local - tn * J.tk;

    const int t = threadIdx.x;
    const int lx = t & 63;
    const int gy = t >> 6;

#pragma unroll
    for (int kk = 0; kk < 16; ++kk) {
        const int k = tkk * 64 + kk * 4 + gy;
        const int n = tn * 64 + lx;
        const float v = (k < J.K) ? J.W[(long)k * J.N + n] : 0.0f;
        tile[lx][kk * 4 + gy] = (bf16)v;
    }
    __syncthreads();
#pragma unroll
    for (int nn = 0; nn < 16; ++nn) {
        const int nloc = nn * 4 + gy;
        const int n = tn * 64 + nloc;
        const int k = tkk * 64 + lx;
        J.Wt[(long)n * J.Kp + k] = tile[nloc][lx];
    }
}

// numerical (B x 13 fp32) -> xpad (B x 64 bf16)
__global__ __launch_bounds__(256) void make_xpad(const float* __restrict__ num,
                                                 bf16* __restrict__ xp) {
    const int idx = blockIdx.x * 256 + threadIdx.x;
    const int b = idx >> 6, c = idx & 63;
    xp[idx] = (bf16)((c < 13) ? num[(long)b * 13 + c] : 0.0f);
}

// ---------------------------------------------------------------------------
// 128x128 tile GEMM (m97 structure, 16x16x32 MFMA) — small/mid layers.
// ~3 blocks/CU at 164 VGPR: cross-block overlap included (m114).
// ---------------------------------------------------------------------------
template <int RELU>
__global__ __launch_bounds__(256) void gemm_bt(const bf16* __restrict__ A,
                                               const bf16* __restrict__ Bt,
                                               const float* __restrict__ bias,
                                               bf16* __restrict__ C,
                                               int M, int N, int K) {
    __shared__ __align__(16) bf16 As[128 * 64];
    __shared__ __align__(16) bf16 Bs[128 * 64];
    const int t = threadIdx.x;
    const int lane = t & 63;
    const int w = t >> 6;
    const int wm = w >> 1, wn = w & 1;
    const long row0 = (long)blockIdx.y * 128;
    const long col0 = (long)blockIdx.x * 128;

    const int srow = t >> 3;
    const int scol = (t & 7) * 8;
    const bf16* Ag = A + (row0 + srow) * (long)K + scol;
    const bf16* Bg = Bt + (col0 + srow) * (long)K + scol;
    bf16* AsB = &As[w * 512];
    bf16* BsB = &Bs[w * 512];

    f32x4 acc[4][4] = {};

    for (int k0 = 0; k0 < K; k0 += 64) {
#pragma unroll
        for (int q = 0; q < 4; ++q) {
            gload_lds16(Ag + (long)q * 32 * K + k0, AsB + q * 2048);
            gload_lds16(Bg + (long)q * 32 * K + k0, BsB + q * 2048);
        }
        __syncthreads();
#pragma unroll
        for (int s = 0; s < 2; ++s) {
            bf16x8 af[4], bv[4];
#pragma unroll
            for (int i = 0; i < 4; ++i)
                af[i] = *(const bf16x8*)&As[(wm * 64 + i * 16 + (lane & 15)) * 64 +
                                            s * 32 + (lane >> 4) * 8];
#pragma unroll
            for (int j = 0; j < 4; ++j)
                bv[j] = *(const bf16x8*)&Bs[(wn * 64 + j * 16 + (lane & 15)) * 64 +
                                            s * 32 + (lane >> 4) * 8];
#pragma unroll
            for (int i = 0; i < 4; ++i)
#pragma unroll
                for (int j = 0; j < 4; ++j)
                    acc[i][j] = __builtin_amdgcn_mfma_f32_16x16x32_bf16(
                        af[i], bv[j], acc[i][j], 0, 0, 0);
        }
        __syncthreads();
    }

    const int r4 = (lane >> 4) * 4;
    const int cn = lane & 15;
#pragma unroll
    for (int j = 0; j < 4; ++j) {
        const long col = col0 + wn * 64 + j * 16 + cn;
        const float bj = bias[col];
#pragma unroll
        for (int i = 0; i < 4; ++i) {
#pragma unroll
            for (int r = 0; r < 4; ++r) {
                const long row = row0 + wm * 64 + i * 16 + r4 + r;
                float v = acc[i][j][r] + bj;
                if (RELU) v = v > 0.0f ? v : 0.0f;
                C[row * (long)N + col] = (bf16)v;
            }
        }
    }
}

// ---------------------------------------------------------------------------
// 256x128 tile GEMM, BK=64, 2-barrier loop, 16x16x32 MFMA, 8 waves (4m x 2n),
// wave tile 64x64 (R6 winner) — big top-MLP layers.
// __launch_bounds__(512,4) -> <=128 VGPR -> 2 blocks/CU; cross-block overlap
// hides barrier drain (m114). Both-sides XOR swizzle slot^=(row&7) (rule #21).
// Requires M%256==0, N%128==0, K%64==0, grid%8==0.
// ---------------------------------------------------------------------------
template <int RELU>
__global__ __launch_bounds__(512, 4) void gemm_bt2(const bf16* __restrict__ A,
                                                   const bf16* __restrict__ Bt,
                                                   const float* __restrict__ bias,
                                                   bf16* __restrict__ C,
                                                   int M, int N, int K, int nbx) {
    __shared__ __align__(16) bf16 As[256 * 64];  // 32 KB
    __shared__ __align__(16) bf16 Bs[128 * 64];  // 16 KB
    const int t = threadIdx.x;
    const int lane = t & 63;
    const int w = t >> 6;            // 0..7
    const int wm = w >> 1, wn = w & 1;

    const int nwg = gridDim.x;
    const int qch = nwg >> 3;
    const int swz = ((int)blockIdx.x & 7) * qch + ((int)blockIdx.x >> 3);
    const int bx = swz % nbx, by = swz / nbx;
    const long row0 = (long)by * 256;
    const long col0 = (long)bx * 128;

    const int srow = t >> 3;   // 0..63
    const int dslot = t & 7;
    const int gsl = dslot ^ (srow & 7);
    const bf16* Ag = A + (row0 + srow) * (long)K + gsl * 8;
    const bf16* Bg = Bt + (col0 + srow) * (long)K + gsl * 8;
    bf16* AsB = &As[w * 512];
    bf16* BsB = &Bs[w * 512];

    const int cm = lane & 15;
    const int kc = lane >> 4;

    f32x4 acc[4][4] = {};

    for (int k0 = 0; k0 < K; k0 += 64) {
#pragma unroll
        for (int q = 0; q < 4; ++q)
            gload_lds16(Ag + (long)q * 64 * K + k0, AsB + q * 4096);
#pragma unroll
        for (int q = 0; q < 2; ++q)
            gload_lds16(Bg + (long)q * 64 * K + k0, BsB + q * 4096);
        __syncthreads();
#pragma unroll
        for (int s = 0; s < 2; ++s) {
            bf16x8 af[4], bv[4];
#pragma unroll
            for (int i = 0; i < 4; ++i) {
                const int r = wm * 64 + i * 16 + cm;
                af[i] = *(const bf16x8*)&As[r * 64 + (((s * 4 + kc) ^ (r & 7)) * 8)];
            }
#pragma unroll
            for (int j = 0; j < 4; ++j) {
                const int r = wn * 64 + j * 16 + cm;
                bv[j] = *(const bf16x8*)&Bs[r * 64 + (((s * 4 + kc) ^ (r & 7)) * 8)];
            }
#pragma unroll
            for (int i = 0; i < 4; ++i)
#pragma unroll
                for (int j = 0; j < 4; ++j)
                    acc[i][j] = __builtin_amdgcn_mfma_f32_16x16x32_bf16(
                        af[i], bv[j], acc[i][j], 0, 0, 0);
        }
        __syncthreads();
    }

    const int r4 = kc * 4;
#pragma unroll
    for (int j = 0; j < 4; ++j) {
        const long col = col0 + wn * 64 + j * 16 + cm;
        const float bj = bias[col];
#pragma unroll
        for (int i = 0; i < 4; ++i) {
#pragma unroll
            for (int r = 0; r < 4; ++r) {
                const long row = row0 + wm * 64 + i * 16 + r4 + r;
                float v = acc[i][j][r] + bj;
                if (RELU) v = v > 0.0f ? v : 0.0f;
                C[row * (long)N + col] = (bf16)v;
            }
        }
    }
}

// ---------------------------------------------------------------------------
// Fused embedding gather + pairwise interaction + top_in assembly.
// ---------------------------------------------------------------------------
__global__ __launch_bounds__(256) void interact_k(const float* __restrict__ emb,
                                                  const int* __restrict__ cat,
                                                  const bf16* __restrict__ bottom,
                                                  bf16* __restrict__ top_in) {
    __shared__ float gram[4][32 * 32];
    __shared__ __align__(16) bf16 rowbuf[4][512];
    const int t = threadIdx.x;
    const int lane = t & 63;
    const int w = t >> 6;
    const long s = (long)blockIdx.x * 4 + w;

    const int rl = lane & 15;
    const int kg = lane >> 4;

    bf16x8 f[2][4];
#pragma unroll
    for (int i = 0; i < 2; ++i) {
        const int r = i * 16 + rl;
        const float* rowp = nullptr;
        if (r >= 1 && r <= 26) {
            const int idx = cat[s * T_CAT + (r - 1)];
            rowp = emb + ((long)(r - 1) * V_SZ + idx) * E_SZ;
        }
#pragma unroll
        for (int ks = 0; ks < 4; ++ks) {
            const int c = ks * 32 + kg * 8;
            bf16x8 v = {};
            if (r == 0) {
                v = *(const bf16x8*)(bottom + s * 128 + c);
            } else if (r <= 26) {
                const float4 v0 = *(const float4*)(rowp + c);
                const float4 v1 = *(const float4*)(rowp + c + 4);
                v[0]=(bf16)v0.x; v[1]=(bf16)v0.y; v[2]=(bf16)v0.z; v[3]=(bf16)v0.w;
                v[4]=(bf16)v1.x; v[5]=(bf16)v1.y; v[6]=(bf16)v1.z; v[7]=(bf16)v1.w;
            }
            f[i][ks] = v;
        }
    }

    f32x4 a00 = {}, a01 = {}, a11 = {};
#pragma unroll
    for (int ks = 0; ks < 4; ++ks) {
        a00 = __builtin_amdgcn_mfma_f32_16x16x32_bf16(f[0][ks], f[0][ks], a00, 0, 0, 0);
        a01 = __builtin_amdgcn_mfma_f32_16x16x32_bf16(f[0][ks], f[1][ks], a01, 0, 0, 0);
        a11 = __builtin_amdgcn_mfma_f32_16x16x32_bf16(f[1][ks], f[1][ks], a11, 0, 0, 0);
    }

    const int r4 = kg * 4;
#pragma unroll
    for (int r = 0; r < 4; ++r) {
        gram[w][(r4 + r) * 32 + rl]           = a00[r];
        gram[w][(r4 + r) * 32 + 16 + rl]      = a01[r];
        gram[w][(16 + r4 + r) * 32 + 16 + rl] = a11[r];
    }
    asm volatile("s_waitcnt lgkmcnt(0)" ::: "memory");
    __builtin_amdgcn_sched_barrier(0);

    if (lane < 16)
        ((bf16x8*)&rowbuf[w][0])[lane] = ((const bf16x8*)(bottom + s * 128))[lane];
    for (int p = lane; p < 351; p += 64) {
        int i = 0, b = 0;
        while (b + (26 - i) <= p) { b += 26 - i; ++i; }
        const int j = p - b + i + 1;
        rowbuf[w][128 + p] = (bf16)gram[w][i * 32 + j];
    }
    if (lane >= 31) rowbuf[w][448 + lane] = (bf16)0.0f;
    asm volatile("s_waitcnt lgkmcnt(0)" ::: "memory");
    __builtin_amdgcn_sched_barrier(0);

    *(bf16x8*)(top_in + s * 512 + lane * 8) = *(const bf16x8*)&rowbuf[w][lane * 8];
}

// ---------------------------------------------------------------------------
// Final layer GEMV.
// ---------------------------------------------------------------------------
__global__ __launch_bounds__(256) void gemv_final(const bf16* __restrict__ A,
                                                  const float* __restrict__ w4,
                                                  const float* __restrict__ b4,
                                                  float* __restrict__ out) {
    const int t = threadIdx.x;
    const int lane = t & 63;
    const int w = t >> 6;
    const long m = (long)blockIdx.x * 4 + w;
    const bf16x4 v = *(const bf16x4*)(A + m * 256 + lane * 4);
    const float4 wv = *(const float4*)(w4 + lane * 4);
    float sum = (float)v[0] * wv.x + (float)v[1] * wv.y + (float)v[2] * wv.z +
                (float)v[3] * wv.w;
#pragma unroll
    for (int off = 32; off > 0; off >>= 1) sum += __shfl_down(sum, off);
    if (lane == 0) out[m] = sum + b4[0];
}

// ---------------------------------------------------------------------------
extern "C" void kernel_launch(void* const* d_in, const int* in_sizes, int n_in,
                              void* d_out, int out_size, void* d_ws, size_t ws_size,
                              hipStream_t stream) {
    const float* numerical = (const float*)d_in[0];
    const int*   cat       = (const int*)d_in[1];
    const float* emb       = (const float*)d_in[2];
    const float* bw0 = (const float*)d_in[3];
    const float* bb0 = (const float*)d_in[4];
    const float* bw1 = (const float*)d_in[5];
    const float* bb1 = (const float*)d_in[6];
    const float* bw2 = (const float*)d_in[7];
    const float* bb2 = (const float*)d_in[8];
    const float* tw0 = (const float*)d_in[9];
    const float* tb0 = (const float*)d_in[10];
    const float* tw1 = (const float*)d_in[11];
    const float* tb1 = (const float*)d_in[12];
    const float* tw2 = (const float*)d_in[13];
    const float* tb2 = (const float*)d_in[14];
    const float* tw3 = (const float*)d_in[15];
    const float* tb3 = (const float*)d_in[16];
    const float* tw4 = (const float*)d_in[17];
    const float* tb4 = (const float*)d_in[18];
    float* out = (float*)d_out;

    char* ws = (char*)d_ws;
    size_t off = 0;
    auto alloc = [&](size_t bytes) {
        char* p = ws + off;
        off += (bytes + 255) & ~(size_t)255;
        return p;
    };
    bf16* wt0b = (bf16*)alloc((size_t)512 * 64 * 2);
    bf16* wt1b = (bf16*)alloc((size_t)256 * 512 * 2);
    bf16* wt2b = (bf16*)alloc((size_t)128 * 256 * 2);
    bf16* wt0t = (bf16*)alloc((size_t)1024 * 512 * 2);
    bf16* wt1t = (bf16*)alloc((size_t)1024 * 1024 * 2);
    bf16* wt2t = (bf16*)alloc((size_t)512 * 1024 * 2);
    bf16* wt3t = (bf16*)alloc((size_t)256 * 512 * 2);
    bf16* xpad = (bf16*)alloc((size_t)B_SZ * 64 * 2);
    bf16* h0   = (bf16*)alloc((size_t)B_SZ * 512 * 2);
    bf16* h1   = (bf16*)alloc((size_t)B_SZ * 256 * 2);
    bf16* bot  = (bf16*)alloc((size_t)B_SZ * 128 * 2);
    bf16* t0   = (bf16*)alloc((size_t)B_SZ * 1024 * 2);
    bf16* t1   = (bf16*)alloc((size_t)B_SZ * 1024 * 2);
    bf16* top_in = h0;
    bf16* t2 = t0;
    bf16* t3 = t1;

    CJobs js;
    js.j[0] = {bw0, wt0b, 16, 512, 64, 0, 1};
    js.j[1] = {bw1, wt1b, 512, 256, 512, 8, 8};
    js.j[2] = {bw2, wt2b, 256, 128, 256, 40, 4};
    js.j[3] = {tw0, wt0t, 480, 1024, 512, 48, 8};
    js.j[4] = {tw1, wt1t, 1024, 1024, 1024, 176, 16};
    js.j[5] = {tw2, wt2t, 1024, 512, 1024, 432, 16};
    js.j[6] = {tw3, wt3t, 512, 256, 512, 560, 8};
    convw_all<<<592, 256, 0, stream>>>(js);

    make_xpad<<<(B_SZ * 64) / 256, 256, 0, stream>>>(numerical, xpad);

    // bottom MLP — l1 moved to gemm_bt (512 blocks, ~3/CU) vs 1-block/CU bt2
    gemm_bt<1><<<dim3(4, 256), 256, 0, stream>>>(xpad, wt0b, bb0, h0, B_SZ, 512, 64);
    gemm_bt<1><<<dim3(2, 256), 256, 0, stream>>>(h0, wt1b, bb1, h1, B_SZ, 256, 512);
    gemm_bt<1><<<dim3(1, 256), 256, 0, stream>>>(h1, wt2b, bb2, bot, B_SZ, 128, 256);

    interact_k<<<B_SZ / 4, 256, 0, stream>>>(emb, cat, bot, top_in);

    // top MLP: big 3 on the R6-winning gemm_bt2; t3 on gemm_bt (512 blocks)
    gemm_bt2<1><<<dim3(1024), 512, 0, stream>>>(top_in, wt0t, tb0, t0, B_SZ, 1024, 512, 8);
    gemm_bt2<1><<<dim3(1024), 512, 0, stream>>>(t0, wt1t, tb1, t1, B_SZ, 1024, 1024, 8);
    gemm_bt2<1><<<dim3(512), 512, 0, stream>>>(t1, wt2t, tb2, t2, B_SZ, 512, 1024, 4);
    gemm_bt<1><<<dim3(2, 256), 256, 0, stream>>>(t2, wt3t, tb3, t3, B_SZ, 256, 512);

    gemv_final<<<B_SZ / 4, 256, 0, stream>>>(t3, tw4, tb4, out);
}